// Round 5
// baseline (78.930 us; speedup 1.0000x reference)
//
#include <hip/hip_runtime.h>
#include <math.h>

#define NROWS 2048
#define DDIM 32
#define REPS 4  // calibration: run compute core 4x; dur4 = OH + k + 3*k_C

// ---------------------------------------------------------------------------
// Single fused kernel (identical to round 4 except Phase C repeated REPS
// times for timing calibration; last rep's results feed the epilogue, so
// output is bit-identical to round 4).
// ---------------------------------------------------------------------------
__global__ __launch_bounds__(256, 1) void HybridKernel_fused(
    const float* __restrict__ x, const float* __restrict__ y,
    float* __restrict__ out) {
  __shared__ float4 sD[2][24 * 128];
  __shared__ float4 sRs[32][16];  // partial sums   [rowgrp][side*8+colquad]
  __shared__ float4 sRq[32][16];  // partial sumsqs
  __shared__ float sNrm[2][128];
  __shared__ float sMu[2][32];
  __shared__ float sInv[2][32];

  const int t = threadIdx.x;
  const int i0 = blockIdx.y * 128;
  const int j0 = blockIdx.x * 128;

  // --- hoist this block's tile loads; latency hides under stats compute ---
  float4 gx[4], gy[4];
#pragma unroll
  for (int rep = 0; rep < 4; ++rep) {
    const int u = t + 256 * rep;
    const int row = u >> 3;
    const int q = u & 7;
    gx[rep] = *reinterpret_cast<const float4*>(&x[(i0 + row) * DDIM + q * 4]);
    gy[rep] = *reinterpret_cast<const float4*>(&y[(j0 + row) * DDIM + q * 4]);
  }

  // --- Phase A: full-input stats, float4-vectorized ---
  {
    const int cq = t & 7;   // column quad 0..7
    const int rg = t >> 3;  // row group 0..31
    const float4* px = reinterpret_cast<const float4*>(x) + rg * 8 + cq;
    const float4* py = reinterpret_cast<const float4*>(y) + rg * 8 + cq;
    float4 sx = {0.f, 0.f, 0.f, 0.f}, qx = {0.f, 0.f, 0.f, 0.f};
    float4 sy = {0.f, 0.f, 0.f, 0.f}, qy = {0.f, 0.f, 0.f, 0.f};
#pragma unroll 4
    for (int i = 0; i < NROWS / 32; ++i) {  // rows rg + 32*i
      const float4 vx = px[(size_t)i * 32 * 8];
      const float4 vy = py[(size_t)i * 32 * 8];
      sx.x += vx.x; qx.x = fmaf(vx.x, vx.x, qx.x);
      sx.y += vx.y; qx.y = fmaf(vx.y, vx.y, qx.y);
      sx.z += vx.z; qx.z = fmaf(vx.z, vx.z, qx.z);
      sx.w += vx.w; qx.w = fmaf(vx.w, vx.w, qx.w);
      sy.x += vy.x; qy.x = fmaf(vy.x, vy.x, qy.x);
      sy.y += vy.y; qy.y = fmaf(vy.y, vy.y, qy.y);
      sy.z += vy.z; qy.z = fmaf(vy.z, vy.z, qy.z);
      sy.w += vy.w; qy.w = fmaf(vy.w, vy.w, qy.w);
    }
    sRs[rg][cq] = sx;
    sRq[rg][cq] = qx;
    sRs[rg][8 + cq] = sy;
    sRq[rg][8 + cq] = qy;
  }
  __syncthreads();
  if (t < 16) {  // t = side*8 + colquad
    float4 S = {0.f, 0.f, 0.f, 0.f}, Q = {0.f, 0.f, 0.f, 0.f};
#pragma unroll 4
    for (int g = 0; g < 32; ++g) {
      const float4 a = sRs[g][t];
      const float4 b = sRq[g][t];
      S.x += a.x; S.y += a.y; S.z += a.z; S.w += a.w;
      Q.x += b.x; Q.y += b.y; Q.z += b.z; Q.w += b.w;
    }
    const float Sa[4] = {S.x, S.y, S.z, S.w};
    const float Qa[4] = {Q.x, Q.y, Q.z, Q.w};
    const int side = t >> 3;
    const int c0 = (t & 7) * 4;
    const float n = (float)NROWS;
#pragma unroll
    for (int k = 0; k < 4; ++k) {
      const float mean = Sa[k] / n;
      const float var = fmaxf((Qa[k] - Sa[k] * mean) / (n - 1.f), 0.f);
      sMu[side][c0 + k] = mean;
      sInv[side][c0 + k] = 1.f / (sqrtf(var) + 1e-8f);
    }
  }
  __syncthreads();

  // --- Phase B: staging from preloaded registers ---
#pragma unroll
  for (int rep = 0; rep < 4; ++rep) {
    const int u = t + 256 * rep;
    const int row = u >> 3;
    const int q = u & 7;
#pragma unroll
    for (int side = 0; side < 2; ++side) {
      const float4 g = side ? gy[rep] : gx[rep];
      const float sc = side ? 1.0f : 0.5f;
      const float gv[4] = {g.x, g.y, g.z, g.w};
      float xn[4], hc[4], hs[4];
      float nrm = 0.f;
#pragma unroll
      for (int k = 0; k < 4; ++k) {
        const int d = q * 4 + k;
        xn[k] = (gv[k] - sMu[side][d]) * sInv[side][d];
        nrm = fmaf(xn[k], xn[k], nrm);
        float sn, cs;
        __sincosf(gv[k], &sn, &cs);
        hc[k] = sc * cs;
        hs[k] = sc * sn;
      }
      sD[side][(16 + q) * 128 + (row ^ q)] =
          make_float4(xn[0], xn[1], xn[2], xn[3]);
      const int dp0 = 2 * q, dp1 = 2 * q + 1;
      sD[side][dp0 * 128 + (row ^ (dp0 & 7))] =
          make_float4(hc[0], hs[0], hc[1], hs[1]);
      sD[side][dp1 * 128 + (row ^ (dp1 & 7))] =
          make_float4(hc[2], hs[2], hc[3], hs[3]);
      nrm += __shfl_xor(nrm, 1);
      nrm += __shfl_xor(nrm, 2);
      nrm += __shfl_xor(nrm, 4);
      if ((t & 7) == 0) sNrm[side][row] = nrm;
    }
  }
  __syncthreads();

  // --- Phase C: 24 phases, double-buffered fragments; repeated REPS times ---
  const int tx = t & 15;
  const int ty = t >> 4;
  const float4* sD0 = &sD[0][0];
  const float4* sD1 = &sD[1][0];

  float acc[8][8];
  float qp[8][8];
  float4 fxA[8], fyA[8], fxB[8], fyB[8];

  auto loadp = [&](int s, float4* FX, float4* FY) {
    const int sw = s & 7;
    const float4* bx = sD0 + s * 128 + (ty ^ sw);
    const float4* by = sD1 + s * 128 + (tx ^ sw);
#pragma unroll
    for (int i = 0; i < 8; ++i) {
      FX[i] = bx[16 * i];
      FY[i] = by[16 * i];
    }
  };
  auto sfromp = [](int p) {
    const int q = (p * 11) >> 5;  // p/3 for p in [0,31]
    const int k = p - 3 * q;
    return (k == 0) ? (16 + q) : (2 * q + k - 1);
  };
  auto compC = [&](const float4* FX, const float4* FY) {
#pragma unroll
    for (int r = 0; r < 8; ++r)
#pragma unroll
      for (int c = 0; c < 8; ++c) {
        float a = acc[r][c];
        a = fmaf(FX[r].x, FY[c].x, a);
        a = fmaf(FX[r].y, FY[c].y, a);
        a = fmaf(FX[r].z, FY[c].z, a);
        a = fmaf(FX[r].w, FY[c].w, a);
        acc[r][c] = a;
      }
  };
  auto compQ = [&](const float4* FX, const float4* FY) {
#pragma unroll
    for (int r = 0; r < 8; ++r)
#pragma unroll
      for (int c = 0; c < 8; ++c) {
        const float t0 = fmaf(FX[r].x, FY[c].x, fmaf(FX[r].y, FY[c].y, 0.5f));
        const float t1 = fmaf(FX[r].z, FY[c].z, fmaf(FX[r].w, FY[c].w, 0.5f));
        qp[r][c] *= t0 * t1;
      }
  };

#pragma unroll 1
  for (int rep4 = 0; rep4 < REPS; ++rep4) {
#pragma unroll
    for (int r = 0; r < 8; ++r)
#pragma unroll
      for (int c = 0; c < 8; ++c) {
        acc[r][c] = 0.f;
        qp[r][c] = 1.f;
      }

    loadp(16, fxA, fyA);  // phase 0 = (q=0, C)
#pragma unroll 1
    for (int p = 0; p < 24; p += 2) {
      loadp(sfromp(p + 1), fxB, fyB);
      if (p % 3 == 0)
        compC(fxA, fyA);
      else
        compQ(fxA, fyA);
      const int p2 = p + 2;
      loadp(p2 < 24 ? sfromp(p2) : 0, fxA, fyA);
      if ((p + 1) % 3 == 0)
        compC(fxB, fyB);
      else
        compQ(fxB, fyB);
    }
    // keep each rep's result live so repeats can't be collapsed
    asm volatile("" : "+v"(acc[0][0]), "+v"(qp[0][0]));
    __builtin_amdgcn_sched_barrier(0);
  }

  // --- epilogue (uses last rep's values; identical math to round 4) ---
  float nx[8], ny[8];
#pragma unroll
  for (int r = 0; r < 8; ++r) nx[r] = sNrm[0][ty + 16 * r];
#pragma unroll
  for (int c = 0; c < 8; ++c) ny[c] = sNrm[1][tx + 16 * c];

#pragma unroll
  for (int r = 0; r < 8; ++r) {
    const int row = i0 + ty + 16 * r;
    float* o = out + (size_t)row * NROWS + j0;
#pragma unroll
    for (int c = 0; c < 8; ++c) {
      const float cl = __expf(2.f * acc[r][c] - nx[r] - ny[c]);
      o[tx + 16 * c] = 0.5f * (cl + qp[r][c]);
    }
  }
}

extern "C" void kernel_launch(void* const* d_in, const int* in_sizes, int n_in,
                              void* d_out, int out_size, void* d_ws,
                              size_t ws_size, hipStream_t stream) {
  const float* x = (const float*)d_in[0];
  const float* y = (const float*)d_in[1];
  float* out = (float*)d_out;

  dim3 grid(NROWS / 128, NROWS / 128);
  HybridKernel_fused<<<grid, 256, 0, stream>>>(x, y, out);
}

// Round 6
// 34.676 us; speedup vs baseline: 2.2762x; 2.2762x over previous
//
#include <hip/hip_runtime.h>
#include <math.h>

#define NROWS 2048
#define DDIM 32

// slot schedule: per quad q (4 d's): C(xn slot 16+q), Q(cs slot 2q), Q(cs 2q+1)
constexpr int slotOf(int p) {
  const int q = p / 3, k = p % 3;
  return k == 0 ? 16 + q : 2 * q + k - 1;
}

struct Frag {
  float4 v[8];
};

template <int S>
__device__ __forceinline__ void loadp(const float4* __restrict__ sD0,
                                      const float4* __restrict__ sD1, int ty,
                                      int tx, Frag& FX, Frag& FY) {
  constexpr int sw = S & 7;
#pragma unroll
  for (int i = 0; i < 8; ++i) {
    FX.v[i] = sD0[S * 128 + (ty ^ sw) + 16 * i];  // offset S*128+16i is immediate
    FY.v[i] = sD1[S * 128 + (tx ^ sw) + 16 * i];
  }
}

__device__ __forceinline__ void compC(const Frag& FX, const Frag& FY,
                                      float (&acc)[8][8]) {
#pragma unroll
  for (int r = 0; r < 8; ++r)
#pragma unroll
    for (int c = 0; c < 8; ++c) {
      float a = acc[r][c];
      a = fmaf(FX.v[r].x, FY.v[c].x, a);
      a = fmaf(FX.v[r].y, FY.v[c].y, a);
      a = fmaf(FX.v[r].z, FY.v[c].z, a);
      a = fmaf(FX.v[r].w, FY.v[c].w, a);
      acc[r][c] = a;
    }
}

__device__ __forceinline__ void compQ(const Frag& FX, const Frag& FY,
                                      float (&qp)[8][8]) {
#pragma unroll
  for (int r = 0; r < 8; ++r)
#pragma unroll
    for (int c = 0; c < 8; ++c) {
      const float t0 =
          fmaf(FX.v[r].x, FY.v[c].x, fmaf(FX.v[r].y, FY.v[c].y, 0.5f));
      const float t1 =
          fmaf(FX.v[r].z, FY.v[c].z, fmaf(FX.v[r].w, FY.v[c].w, 0.5f));
      qp[r][c] *= t0 * t1;
    }
}

template <int P>
__device__ __forceinline__ void pipe(const float4* __restrict__ sD0,
                                     const float4* __restrict__ sD1, int ty,
                                     int tx, Frag& Ax, Frag& Ay, Frag& Bx,
                                     Frag& By, float (&acc)[8][8],
                                     float (&qp)[8][8]) {
  if constexpr (P >= 24) {
    return;
  } else {
    Frag& CX = (P & 1) ? Bx : Ax;  // compile-time select
    Frag& CY = (P & 1) ? By : Ay;
    Frag& NX = (P & 1) ? Ax : Bx;
    Frag& NY = (P & 1) ? Ay : By;
    if constexpr (P + 1 < 24)
      loadp<slotOf(P + 1)>(sD0, sD1, ty, tx, NX, NY);
    __builtin_amdgcn_sched_barrier(0);  // pin: issue next loads before compute
    if constexpr (P % 3 == 0)
      compC(CX, CY, acc);
    else
      compQ(CX, CY, qp);
    pipe<P + 1>(sD0, sD1, ty, tx, Ax, Ay, Bx, By, acc, qp);
  }
}

// ---------------------------------------------------------------------------
// Single fused kernel. 128x128 tile per 256-thread block, 8x8 micro-tile.
// Phase A: per-block redundant full-input stats (L2-resident inputs).
// Phase B: stage xn / (0.5cos,0.5sin) / (cos,sin) into XOR-swizzled LDS.
// Phase C: fully-unrolled 24-phase static pipeline, explicit double buffer.
// ---------------------------------------------------------------------------
__global__ __launch_bounds__(256, 1) void HybridKernel_fused(
    const float* __restrict__ x, const float* __restrict__ y,
    float* __restrict__ out) {
  __shared__ float4 sD[2][24 * 128];
  __shared__ float4 sRs[32][16];  // partial sums   [rowgrp][side*8+colquad]
  __shared__ float4 sRq[32][16];  // partial sumsqs
  __shared__ float sNrm[2][128];
  __shared__ float sMu[2][32];
  __shared__ float sInv[2][32];

  const int t = threadIdx.x;
  const int i0 = blockIdx.y * 128;
  const int j0 = blockIdx.x * 128;

  // --- hoist this block's tile loads; latency hides under stats compute ---
  float4 gx[4], gy[4];
#pragma unroll
  for (int rep = 0; rep < 4; ++rep) {
    const int u = t + 256 * rep;
    const int row = u >> 3;
    const int q = u & 7;
    gx[rep] = *reinterpret_cast<const float4*>(&x[(i0 + row) * DDIM + q * 4]);
    gy[rep] = *reinterpret_cast<const float4*>(&y[(j0 + row) * DDIM + q * 4]);
  }

  // --- Phase A: full-input stats, float4-vectorized ---
  {
    const int cq = t & 7;   // column quad 0..7
    const int rg = t >> 3;  // row group 0..31
    const float4* px = reinterpret_cast<const float4*>(x) + rg * 8 + cq;
    const float4* py = reinterpret_cast<const float4*>(y) + rg * 8 + cq;
    float4 sx = {0.f, 0.f, 0.f, 0.f}, qx = {0.f, 0.f, 0.f, 0.f};
    float4 sy = {0.f, 0.f, 0.f, 0.f}, qy = {0.f, 0.f, 0.f, 0.f};
#pragma unroll 4
    for (int i = 0; i < NROWS / 32; ++i) {  // rows rg + 32*i
      const float4 vx = px[(size_t)i * 32 * 8];
      const float4 vy = py[(size_t)i * 32 * 8];
      sx.x += vx.x; qx.x = fmaf(vx.x, vx.x, qx.x);
      sx.y += vx.y; qx.y = fmaf(vx.y, vx.y, qx.y);
      sx.z += vx.z; qx.z = fmaf(vx.z, vx.z, qx.z);
      sx.w += vx.w; qx.w = fmaf(vx.w, vx.w, qx.w);
      sy.x += vy.x; qy.x = fmaf(vy.x, vy.x, qy.x);
      sy.y += vy.y; qy.y = fmaf(vy.y, vy.y, qy.y);
      sy.z += vy.z; qy.z = fmaf(vy.z, vy.z, qy.z);
      sy.w += vy.w; qy.w = fmaf(vy.w, vy.w, qy.w);
    }
    sRs[rg][cq] = sx;
    sRq[rg][cq] = qx;
    sRs[rg][8 + cq] = sy;
    sRq[rg][8 + cq] = qy;
  }
  __syncthreads();
  if (t < 16) {  // t = side*8 + colquad
    float4 S = {0.f, 0.f, 0.f, 0.f}, Q = {0.f, 0.f, 0.f, 0.f};
#pragma unroll 4
    for (int g = 0; g < 32; ++g) {
      const float4 a = sRs[g][t];
      const float4 b = sRq[g][t];
      S.x += a.x; S.y += a.y; S.z += a.z; S.w += a.w;
      Q.x += b.x; Q.y += b.y; Q.z += b.z; Q.w += b.w;
    }
    const float Sa[4] = {S.x, S.y, S.z, S.w};
    const float Qa[4] = {Q.x, Q.y, Q.z, Q.w};
    const int side = t >> 3;
    const int c0 = (t & 7) * 4;
    const float n = (float)NROWS;
#pragma unroll
    for (int k = 0; k < 4; ++k) {
      const float mean = Sa[k] / n;
      const float var = fmaxf((Qa[k] - Sa[k] * mean) / (n - 1.f), 0.f);
      sMu[side][c0 + k] = mean;
      sInv[side][c0 + k] = 1.f / (sqrtf(var) + 1e-8f);
    }
  }
  __syncthreads();

  // --- Phase B: staging from preloaded registers ---
#pragma unroll
  for (int rep = 0; rep < 4; ++rep) {
    const int u = t + 256 * rep;
    const int row = u >> 3;
    const int q = u & 7;
#pragma unroll
    for (int side = 0; side < 2; ++side) {
      const float4 g = side ? gy[rep] : gx[rep];
      const float sc = side ? 1.0f : 0.5f;
      const float gv[4] = {g.x, g.y, g.z, g.w};
      float xn[4], hc[4], hs[4];
      float nrm = 0.f;
#pragma unroll
      for (int k = 0; k < 4; ++k) {
        const int d = q * 4 + k;
        xn[k] = (gv[k] - sMu[side][d]) * sInv[side][d];
        nrm = fmaf(xn[k], xn[k], nrm);
        float sn, cs;
        __sincosf(gv[k], &sn, &cs);
        hc[k] = sc * cs;
        hs[k] = sc * sn;
      }
      sD[side][(16 + q) * 128 + (row ^ q)] =
          make_float4(xn[0], xn[1], xn[2], xn[3]);
      const int dp0 = 2 * q, dp1 = 2 * q + 1;
      sD[side][dp0 * 128 + (row ^ (dp0 & 7))] =
          make_float4(hc[0], hs[0], hc[1], hs[1]);
      sD[side][dp1 * 128 + (row ^ (dp1 & 7))] =
          make_float4(hc[2], hs[2], hc[3], hs[3]);
      nrm += __shfl_xor(nrm, 1);
      nrm += __shfl_xor(nrm, 2);
      nrm += __shfl_xor(nrm, 4);
      if ((t & 7) == 0) sNrm[side][row] = nrm;
    }
  }
  __syncthreads();

  // --- Phase C: static 24-phase pipeline ---
  const int tx = t & 15;
  const int ty = t >> 4;
  const float4* sD0 = &sD[0][0];
  const float4* sD1 = &sD[1][0];

  float acc[8][8];
  float qp[8][8];
#pragma unroll
  for (int r = 0; r < 8; ++r)
#pragma unroll
    for (int c = 0; c < 8; ++c) {
      acc[r][c] = 0.f;
      qp[r][c] = 1.f;
    }

  Frag Ax, Ay, Bx, By;
  loadp<slotOf(0)>(sD0, sD1, ty, tx, Ax, Ay);  // prologue: slot 16 -> A
  pipe<0>(sD0, sD1, ty, tx, Ax, Ay, Bx, By, acc, qp);

  // --- epilogue ---
  float nx[8], ny[8];
#pragma unroll
  for (int r = 0; r < 8; ++r) nx[r] = sNrm[0][ty + 16 * r];
#pragma unroll
  for (int c = 0; c < 8; ++c) ny[c] = sNrm[1][tx + 16 * c];

#pragma unroll
  for (int r = 0; r < 8; ++r) {
    const int row = i0 + ty + 16 * r;
    float* o = out + (size_t)row * NROWS + j0;
#pragma unroll
    for (int c = 0; c < 8; ++c) {
      const float cl = __expf(2.f * acc[r][c] - nx[r] - ny[c]);
      o[tx + 16 * c] = 0.5f * (cl + qp[r][c]);
    }
  }
}

extern "C" void kernel_launch(void* const* d_in, const int* in_sizes, int n_in,
                              void* d_out, int out_size, void* d_ws,
                              size_t ws_size, hipStream_t stream) {
  const float* x = (const float*)d_in[0];
  const float* y = (const float*)d_in[1];
  float* out = (float*)d_out;

  dim3 grid(NROWS / 128, NROWS / 128);
  HybridKernel_fused<<<grid, 256, 0, stream>>>(x, y, out);
}

// Round 7
// 26.616 us; speedup vs baseline: 2.9655x; 1.3028x over previous
//
#include <hip/hip_runtime.h>
#include <math.h>

#define NROWS 2048
#define DDIM 32
#define SBLK 16               // stats blocks per array
#define SROWS (NROWS / SBLK)  // 128 rows per stats block

// ---------------------------------------------------------------------------
// Stage 1: coalesced per-column partial sums. 32 blocks; block b covers
// array a=b>>4, rows [blk*128, blk*128+128). part[b][0:32]=sum, [32:64]=sumsq.
// ---------------------------------------------------------------------------
__global__ __launch_bounds__(256) void HybridKernel_stats_partial(
    const float* __restrict__ x, const float* __restrict__ y,
    float* __restrict__ part) {
  const int b = blockIdx.x;
  const int a = b >> 4;
  const int blk = b & (SBLK - 1);
  const float* in = a ? y : x;
  const int t = threadIdx.x;
  const int col = t & 31;
  const int rg = t >> 5;  // 0..7
  float s = 0.f, s2 = 0.f;
  const int r0 = blk * SROWS + rg;
#pragma unroll
  for (int i = 0; i < SROWS / 8; ++i) {
    float v = in[(r0 + i * 8) * DDIM + col];
    s += v;
    s2 = fmaf(v, v, s2);
  }
  __shared__ float ss[8][32];
  __shared__ float sq[8][32];
  ss[rg][col] = s;
  sq[rg][col] = s2;
  __syncthreads();
  if (t < 32) {
    float S = 0.f, Q = 0.f;
#pragma unroll
    for (int g = 0; g < 8; ++g) {
      S += ss[g][t];
      Q += sq[g][t];
    }
    part[b * 64 + t] = S;
    part[b * 64 + 32 + t] = Q;
  }
}

// ---------------------------------------------------------------------------
// Stage 2: 128x128 tile per 512-thread block (8 waves = 2 waves/SIMD for TLP
// overlap of LDS and VALU pipes). Micro-tile 8x4: rows ty+16r (ty=t>>5),
// cols tx+32c (tx=t&31).
// LDS slot array sD[side][s*128 + (idx ^ (s&7))], 24 slots per side:
//   s = 0..15 : cos/sin d-pair dp=s -> float4 (hc0,hs0,hc1,hs1), d = 2s,2s+1
//   s = 16..23: xn quad q=s-16     -> float4 xn[4q..4q+3]
// x side folds ALPHA: hc=0.5cos(x), hs=0.5sin(x); y side plain cos/sin.
// classical = exp(2*dot - nx - ny); quantum term = 0.5 + hcx*cy + hsx*sy.
// ---------------------------------------------------------------------------
__global__ __launch_bounds__(512, 2) void HybridKernel_main(
    const float* __restrict__ x, const float* __restrict__ y,
    const float* __restrict__ part, float* __restrict__ out) {
  __shared__ float4 sD[2][24 * 128];
  __shared__ float sNrm[2][128];
  __shared__ float sMu[2][32];
  __shared__ float sInv[2][32];

  const int t = threadIdx.x;
  const int i0 = blockIdx.y * 128;
  const int j0 = blockIdx.x * 128;

  // --- hoist tile global loads (independent of stats) ---
  float4 gx[2], gy[2];
#pragma unroll
  for (int rep = 0; rep < 2; ++rep) {
    const int u = t + 512 * rep;
    const int row = u >> 3;
    const int q = u & 7;
    gx[rep] = *reinterpret_cast<const float4*>(&x[(i0 + row) * DDIM + q * 4]);
    gy[rep] = *reinterpret_cast<const float4*>(&y[(j0 + row) * DDIM + q * 4]);
  }

  // --- finalize stats (mean, 1/(std+eps), ddof=1) from partials ---
  if (t < 64) {
    const int a = t >> 5;
    const int c = t & 31;
    float S = 0.f, Q = 0.f;
#pragma unroll
    for (int bb = 0; bb < SBLK; ++bb) {
      S += part[(a * SBLK + bb) * 64 + c];
      Q += part[(a * SBLK + bb) * 64 + 32 + c];
    }
    const float n = (float)NROWS;
    const float mean = S / n;
    const float var = fmaxf((Q - S * mean) / (n - 1.f), 0.f);
    sMu[a][c] = mean;
    sInv[a][c] = 1.f / (sqrtf(var) + 1e-8f);
  }
  __syncthreads();

  // --- staging: 1024 (row,quad) units per side, 2 reps over 512 threads ---
#pragma unroll
  for (int rep = 0; rep < 2; ++rep) {
    const int u = t + 512 * rep;
    const int row = u >> 3;
    const int q = u & 7;
#pragma unroll
    for (int side = 0; side < 2; ++side) {
      const float4 g = side ? gy[rep] : gx[rep];
      const float sc = side ? 1.0f : 0.5f;
      const float gv[4] = {g.x, g.y, g.z, g.w};
      float xn[4], hc[4], hs[4];
      float nrm = 0.f;
#pragma unroll
      for (int k = 0; k < 4; ++k) {
        const int d = q * 4 + k;
        xn[k] = (gv[k] - sMu[side][d]) * sInv[side][d];
        nrm = fmaf(xn[k], xn[k], nrm);
        float sn, cs;
        __sincosf(gv[k], &sn, &cs);
        hc[k] = sc * cs;
        hs[k] = sc * sn;
      }
      sD[side][(16 + q) * 128 + (row ^ q)] =
          make_float4(xn[0], xn[1], xn[2], xn[3]);
      const int dp0 = 2 * q, dp1 = 2 * q + 1;
      sD[side][dp0 * 128 + (row ^ (dp0 & 7))] =
          make_float4(hc[0], hs[0], hc[1], hs[1]);
      sD[side][dp1 * 128 + (row ^ (dp1 & 7))] =
          make_float4(hc[2], hs[2], hc[3], hs[3]);
      nrm += __shfl_xor(nrm, 1);
      nrm += __shfl_xor(nrm, 2);
      nrm += __shfl_xor(nrm, 4);
      if ((t & 7) == 0) sNrm[side][row] = nrm;
    }
  }
  __syncthreads();

  // --- main compute: 8x4 outputs per thread, 24 phases ---
  const int tx = t & 31;
  const int ty = t >> 5;
  const float4* sD0 = &sD[0][0];
  const float4* sD1 = &sD[1][0];

  float acc[8][4];
  float qp[8][4];
#pragma unroll
  for (int r = 0; r < 8; ++r)
#pragma unroll
    for (int c = 0; c < 4; ++c) {
      acc[r][c] = 0.f;
      qp[r][c] = 1.f;
    }

#pragma unroll
  for (int q = 0; q < 8; ++q) {
    // phase C: xn quad (slot 16+q)
    {
      const int S = 16 + q;
      const int sw = S & 7;
      float4 FX[8], FY[4];
#pragma unroll
      for (int i = 0; i < 8; ++i) FX[i] = sD0[S * 128 + ((ty + 16 * i) ^ sw)];
#pragma unroll
      for (int j = 0; j < 4; ++j) FY[j] = sD1[S * 128 + ((tx + 32 * j) ^ sw)];
#pragma unroll
      for (int r = 0; r < 8; ++r)
#pragma unroll
        for (int c = 0; c < 4; ++c) {
          float a = acc[r][c];
          a = fmaf(FX[r].x, FY[c].x, a);
          a = fmaf(FX[r].y, FY[c].y, a);
          a = fmaf(FX[r].z, FY[c].z, a);
          a = fmaf(FX[r].w, FY[c].w, a);
          acc[r][c] = a;
        }
    }
    // phases Q0, Q1: cos/sin pairs (slots 2q, 2q+1)
#pragma unroll
    for (int h = 0; h < 2; ++h) {
      const int S = 2 * q + h;
      const int sw = S & 7;
      float4 FX[8], FY[4];
#pragma unroll
      for (int i = 0; i < 8; ++i) FX[i] = sD0[S * 128 + ((ty + 16 * i) ^ sw)];
#pragma unroll
      for (int j = 0; j < 4; ++j) FY[j] = sD1[S * 128 + ((tx + 32 * j) ^ sw)];
#pragma unroll
      for (int r = 0; r < 8; ++r)
#pragma unroll
        for (int c = 0; c < 4; ++c) {
          const float t0 =
              fmaf(FX[r].x, FY[c].x, fmaf(FX[r].y, FY[c].y, 0.5f));
          const float t1 =
              fmaf(FX[r].z, FY[c].z, fmaf(FX[r].w, FY[c].w, 0.5f));
          qp[r][c] *= t0 * t1;
        }
    }
  }

  // --- epilogue ---
  float nx[8], ny[4];
#pragma unroll
  for (int r = 0; r < 8; ++r) nx[r] = sNrm[0][ty + 16 * r];
#pragma unroll
  for (int c = 0; c < 4; ++c) ny[c] = sNrm[1][tx + 32 * c];

#pragma unroll
  for (int r = 0; r < 8; ++r) {
    const int row = i0 + ty + 16 * r;
    float* o = out + (size_t)row * NROWS + j0;
#pragma unroll
    for (int c = 0; c < 4; ++c) {
      const float cl = __expf(2.f * acc[r][c] - nx[r] - ny[c]);
      o[tx + 32 * c] = 0.5f * (cl + qp[r][c]);
    }
  }
}

extern "C" void kernel_launch(void* const* d_in, const int* in_sizes, int n_in,
                              void* d_out, int out_size, void* d_ws,
                              size_t ws_size, hipStream_t stream) {
  const float* x = (const float*)d_in[0];
  const float* y = (const float*)d_in[1];
  float* part = (float*)d_ws;  // 2*SBLK*64 = 2048 floats
  float* out = (float*)d_out;

  HybridKernel_stats_partial<<<2 * SBLK, 256, 0, stream>>>(x, y, part);
  dim3 grid(NROWS / 128, NROWS / 128);
  HybridKernel_main<<<grid, 512, 0, stream>>>(x, y, part, out);
}